// Round 17
// baseline (282.377 us; speedup 1.0000x reference)
//
#include <hip/hip_runtime.h>

#define N_NODES   10000
#define N_EDGES   640000
#define DIM       128
#define N_GRAPHS  16
#define N_CLASSES 10

typedef unsigned int uint;
typedef unsigned short ushort;

__device__ __forceinline__ float bf2f(uint lo16) {
    return __uint_as_float(lo16 << 16);
}
__device__ __forceinline__ ushort f2bf(float f) {
    uint u = __float_as_uint(f);
    u += 0x7fffu + ((u >> 16) & 1u);      // round-to-nearest-even
    return (ushort)(u >> 16);
}

// ---------------------------------------------------------------------------
// K0: x (fp32) -> xb (bf16, 2.56 MB: fits per-XCD L2). uint = 2 channels.
// ---------------------------------------------------------------------------
__global__ __launch_bounds__(256) void conv_bf16(
    const float* __restrict__ x, uint* __restrict__ xb)
{
    const int idx = blockIdx.x * 256 + threadIdx.x;     // 1250 blocks exact
    const float4 v = ((const float4*)x)[idx];
    uint lo = (uint)f2bf(v.x) | ((uint)f2bf(v.y) << 16);
    uint hi = (uint)f2bf(v.z) | ((uint)f2bf(v.w) << 16);
    ((uint2*)xb)[idx] = make_uint2(lo, hi);
}

// ---------------------------------------------------------------------------
// K1: histogram of dst — 4 edges/thread
// ---------------------------------------------------------------------------
__global__ __launch_bounds__(256) void hist_dst(
    const int* __restrict__ dst, int* __restrict__ cnt)
{
    const int base = (blockIdx.x * 256 + threadIdx.x) * 4;   // 625 blocks exact
    const int d0 = dst[base + 0];
    const int d1 = dst[base + 1];
    const int d2 = dst[base + 2];
    const int d3 = dst[base + 3];
    atomicAdd(&cnt[d0], 1);
    atomicAdd(&cnt[d1], 1);
    atomicAdd(&cnt[d2], 1);
    atomicAdd(&cnt[d3], 1);
}

// ---------------------------------------------------------------------------
// K2: per-graph node counts (batch_ids) -> gcnt (float)
// ---------------------------------------------------------------------------
__global__ __launch_bounds__(256) void count_nodes(
    const int* __restrict__ bid, float* __restrict__ gcnt)
{
    __shared__ int h[N_GRAPHS];
    const int t = threadIdx.x;
    if (t < N_GRAPHS) h[t] = 0;
    __syncthreads();
    for (int n = t; n < N_NODES; n += 256) atomicAdd(&h[bid[n]], 1);
    __syncthreads();
    if (t < N_GRAPHS) gcnt[t] = (float)h[t];
}

// ---------------------------------------------------------------------------
// K3: exclusive prefix sum of cnt[10000] -> cursor (single block)
// ---------------------------------------------------------------------------
__global__ __launch_bounds__(1024) void scan_k(
    const int* __restrict__ cnt, int* __restrict__ cursor)
{
    __shared__ int s[1024];
    const int t = threadIdx.x;
    int local[10];
    int sum = 0;
    if (t < 1000) {
        for (int j = 0; j < 10; ++j) { local[j] = sum; sum += cnt[t * 10 + j]; }
    }
    s[t] = (t < 1000) ? sum : 0;
    __syncthreads();
    for (int st = 1; st < 1024; st <<= 1) {
        int v = (t >= st) ? s[t - st] : 0;
        __syncthreads();
        s[t] += v;
        __syncthreads();
    }
    if (t < 1000) {
        const int off = (t == 0) ? 0 : s[t - 1];
        for (int j = 0; j < 10; ++j) cursor[t * 10 + j] = off + local[j];
    }
}

// ---------------------------------------------------------------------------
// K4: fill CSR — 4 edges/thread; pairs[pos] = (src, edge_id), grouped by dst
// ---------------------------------------------------------------------------
__global__ __launch_bounds__(256) void fill_csr(
    const int* __restrict__ src, const int* __restrict__ dst,
    int* __restrict__ cursor, uint2* __restrict__ pairs)
{
    const int base = (blockIdx.x * 256 + threadIdx.x) * 4;   // 625 blocks exact
    const int d0 = dst[base + 0];
    const int d1 = dst[base + 1];
    const int d2 = dst[base + 2];
    const int d3 = dst[base + 3];
    const int s0 = src[base + 0];
    const int s1 = src[base + 1];
    const int s2 = src[base + 2];
    const int s3 = src[base + 3];
    const int p0 = atomicAdd(&cursor[d0], 1);
    const int p1 = atomicAdd(&cursor[d1], 1);
    const int p2 = atomicAdd(&cursor[d2], 1);
    const int p3 = atomicAdd(&cursor[d3], 1);
    pairs[p0] = make_uint2((uint)s0, (uint)(base + 0));
    pairs[p1] = make_uint2((uint)s1, (uint)(base + 1));
    pairs[p2] = make_uint2((uint)s2, (uint)(base + 2));
    pairs[p3] = make_uint2((uint)s3, (uint)(base + 3));
}

// ---------------------------------------------------------------------------
// K5: XAGG[n] = sum over in-edges of xb[src]. Wave per node; 8-deep unroll.
// ---------------------------------------------------------------------------
__global__ __launch_bounds__(256) void gather_xb(
    const uint* __restrict__ xb,
    const int* __restrict__ cnt, const int* __restrict__ cursor,
    const uint2* __restrict__ pairs,
    float* __restrict__ XAGG)
{
    const int n    = blockIdx.x * 4 + (threadIdx.x >> 6);
    const int lane = threadIdx.x & 63;
    const int end  = cursor[n];
    int i = end - cnt[n];

    float a0 = 0.f, b0 = 0.f, a1 = 0.f, b1 = 0.f;
    float a2 = 0.f, b2 = 0.f, a3 = 0.f, b3 = 0.f;

    for (; i + 8 <= end; i += 8) {
        const uint v0 = xb[pairs[i + 0].x * 64 + lane];
        const uint v1 = xb[pairs[i + 1].x * 64 + lane];
        const uint v2 = xb[pairs[i + 2].x * 64 + lane];
        const uint v3 = xb[pairs[i + 3].x * 64 + lane];
        const uint v4 = xb[pairs[i + 4].x * 64 + lane];
        const uint v5 = xb[pairs[i + 5].x * 64 + lane];
        const uint v6 = xb[pairs[i + 6].x * 64 + lane];
        const uint v7 = xb[pairs[i + 7].x * 64 + lane];
        a0 += bf2f(v0 & 0xffffu); b0 += bf2f(v0 >> 16);
        a1 += bf2f(v1 & 0xffffu); b1 += bf2f(v1 >> 16);
        a2 += bf2f(v2 & 0xffffu); b2 += bf2f(v2 >> 16);
        a3 += bf2f(v3 & 0xffffu); b3 += bf2f(v3 >> 16);
        a0 += bf2f(v4 & 0xffffu); b0 += bf2f(v4 >> 16);
        a1 += bf2f(v5 & 0xffffu); b1 += bf2f(v5 >> 16);
        a2 += bf2f(v6 & 0xffffu); b2 += bf2f(v6 >> 16);
        a3 += bf2f(v7 & 0xffffu); b3 += bf2f(v7 >> 16);
    }
    for (; i < end; ++i) {
        const uint v = xb[pairs[i].x * 64 + lane];
        a0 += bf2f(v & 0xffffu); b0 += bf2f(v >> 16);
    }
    float2 s;
    s.x = (a0 + a1) + (a2 + a3);
    s.y = (b0 + b1) + (b2 + b3);
    *(float2*)&XAGG[n * DIM + lane * 2] = s;
}

// ---------------------------------------------------------------------------
// K6: fused (8 rows/block, 1250 blocks):
//     z = relu(XAGG@W_in + x@W_self + b)  (LDS only)
//     + per-graph sums (run-compressed atomics)
//     + U12 = z @ [W_e1_top | W_e1_bot] (+b_e1), bf16 interleaved
// ---------------------------------------------------------------------------
#define ZROWS 8
__global__ __launch_bounds__(256) void gemm_zu(
    const float* __restrict__ XAGG_in, const float* __restrict__ x,
    const float* __restrict__ W_in, const float* __restrict__ W_self,
    const float* __restrict__ b, const int* __restrict__ bid,
    const float* __restrict__ W_e1, const float* __restrict__ b_e1,
    float* __restrict__ gsum, ushort* __restrict__ U12)
{
    __shared__ float sa[ZROWS * DIM];
    __shared__ float sb[ZROWS * DIM];
    __shared__ int sbid[ZROWS];
    const int base = blockIdx.x * ZROWS;
    const int t = threadIdx.x;
    {
        const float4* ga = (const float4*)(XAGG_in + base * DIM);
        const float4* gb = (const float4*)(x + base * DIM);
        float4* la = (float4*)sa;
        float4* lb = (float4*)sb;
        for (int i = t; i < ZROWS * DIM / 4; i += 256) { la[i] = ga[i]; lb[i] = gb[i]; }
        if (t < ZROWS) sbid[t] = bid[base + t];
    }
    __syncthreads();

    const int half = t >> 7, c = t & 127;

    // --- matmul 1: half0 = XAGG@W_in, half1 = x@W_self ---
    {
        const float* __restrict__ W = half ? W_self : W_in;
        const float4* A4 = (const float4*)(half ? sb : sa);
        float acc[ZROWS];
#pragma unroll
        for (int r = 0; r < ZROWS; ++r) acc[r] = 0.f;
        for (int k4 = 0; k4 < DIM / 4; ++k4) {
            const float w0 = W[(k4 * 4 + 0) * DIM + c];
            const float w1 = W[(k4 * 4 + 1) * DIM + c];
            const float w2 = W[(k4 * 4 + 2) * DIM + c];
            const float w3 = W[(k4 * 4 + 3) * DIM + c];
#pragma unroll
            for (int r = 0; r < ZROWS; ++r) {
                const float4 xv = A4[r * (DIM / 4) + k4];
                acc[r] = fmaf(xv.x, w0, acc[r]);
                acc[r] = fmaf(xv.y, w1, acc[r]);
                acc[r] = fmaf(xv.z, w2, acc[r]);
                acc[r] = fmaf(xv.w, w3, acc[r]);
            }
        }
        __syncthreads();
        if (half) {
#pragma unroll
            for (int r = 0; r < ZROWS; ++r) sb[r * DIM + c] = acc[r];
        }
        __syncthreads();
        if (!half) {
            const float bv = b[c];
            float run = 0.f;
            int cur = sbid[0];
#pragma unroll
            for (int r = 0; r < ZROWS; ++r) {
                const float z = fmaxf(acc[r] + sb[r * DIM + c] + bv, 0.f);
                sa[r * DIM + c] = z;                    // z lives in LDS only
                const int g = sbid[r];
                if (g != cur) { unsafeAtomicAdd(&gsum[cur * DIM + c], run); run = 0.f; cur = g; }
                run += z;
            }
            unsafeAtomicAdd(&gsum[cur * DIM + c], run);
        }
        __syncthreads();
    }

    // --- matmul 2: U12 = z @ [W_e1_top | W_e1_bot] ---
    {
        const float* __restrict__ W = W_e1 + half * 128 * DIM;
        const float4* Z4 = (const float4*)sa;
        float acc[ZROWS];
#pragma unroll
        for (int r = 0; r < ZROWS; ++r) acc[r] = 0.f;
        for (int k4 = 0; k4 < DIM / 4; ++k4) {
            const float w0 = W[(k4 * 4 + 0) * DIM + c];
            const float w1 = W[(k4 * 4 + 1) * DIM + c];
            const float w2 = W[(k4 * 4 + 2) * DIM + c];
            const float w3 = W[(k4 * 4 + 3) * DIM + c];
#pragma unroll
            for (int r = 0; r < ZROWS; ++r) {
                const float4 xv = Z4[r * (DIM / 4) + k4];
                acc[r] = fmaf(xv.x, w0, acc[r]);
                acc[r] = fmaf(xv.y, w1, acc[r]);
                acc[r] = fmaf(xv.z, w2, acc[r]);
                acc[r] = fmaf(xv.w, w3, acc[r]);
            }
        }
        const float bv = half ? 0.f : b_e1[c];
        for (int r = 0; r < ZROWS; ++r)
            U12[(base + r) * 256 + half * 128 + c] = f2bf(acc[r] + bv);
    }
}

// ---------------------------------------------------------------------------
// K8: edge MLP in CSR order. 16-lane group per dst node; U2[d] cached in
// registers; per edge one coalesced 256B U1-row read; out[eid] scatter.
// ---------------------------------------------------------------------------
__device__ __forceinline__ void ch2(uint a, uint b, float wl, float wh,
                                    float& accl, float& acch)
{
    const float fl = fmaxf(__uint_as_float(a << 16) + __uint_as_float(b << 16), 0.f);
    const float fh = fmaxf(__uint_as_float(a & 0xffff0000u) + __uint_as_float(b & 0xffff0000u), 0.f);
    accl = fmaf(fl, wl, accl);
    acch = fmaf(fh, wh, acch);
}

__global__ __launch_bounds__(256) void edge_mlp4(
    const ushort* __restrict__ U12,
    const int* __restrict__ cnt, const int* __restrict__ cursor,
    const uint2* __restrict__ pairs,
    const float* __restrict__ W_e2, const float* __restrict__ b_e2,
    float* __restrict__ out)
{
    __shared__ float ws[DIM];
    const int t = threadIdx.x;
    if (t < DIM) ws[t] = W_e2[t];
    __syncthreads();

    const int l16 = t & 15;
    const int grp = t >> 4;
    const int n   = blockIdx.x * 16 + grp;         // 625 blocks × 16 = 10000

    const int end = cursor[n];
    int i = end - cnt[n];

    const uint4 u2 = *(const uint4*)(U12 + n * 256 + 128 + l16 * 8);
    const float4 w0 = ((const float4*)ws)[l16 * 2 + 0];
    const float4 w1 = ((const float4*)ws)[l16 * 2 + 1];
    const float be2 = b_e2[0];

    for (; i + 2 <= end; i += 2) {
        const uint2 pa = pairs[i];
        const uint2 pb = pairs[i + 1];
        const uint4 A = *(const uint4*)(U12 + pa.x * 256 + l16 * 8);
        const uint4 B = *(const uint4*)(U12 + pb.x * 256 + l16 * 8);
        float p0 = 0.f, p1 = 0.f, q0 = 0.f, q1 = 0.f;
        ch2(A.x, u2.x, w0.x, w0.y, p0, p1);
        ch2(A.y, u2.y, w0.z, w0.w, p0, p1);
        ch2(A.z, u2.z, w1.x, w1.y, p0, p1);
        ch2(A.w, u2.w, w1.z, w1.w, p0, p1);
        ch2(B.x, u2.x, w0.x, w0.y, q0, q1);
        ch2(B.y, u2.y, w0.z, w0.w, q0, q1);
        ch2(B.z, u2.z, w1.x, w1.y, q0, q1);
        ch2(B.w, u2.w, w1.z, w1.w, q0, q1);
        float p = p0 + p1;
        float q = q0 + q1;
#pragma unroll
        for (int off = 8; off >= 1; off >>= 1) {
            p += __shfl_xor(p, off);
            q += __shfl_xor(q, off);
        }
        if (l16 == 0) { out[pa.y] = p + be2; out[pb.y] = q + be2; }
    }
    if (i < end) {
        const uint2 pa = pairs[i];
        const uint4 A = *(const uint4*)(U12 + pa.x * 256 + l16 * 8);
        float p0 = 0.f, p1 = 0.f;
        ch2(A.x, u2.x, w0.x, w0.y, p0, p1);
        ch2(A.y, u2.y, w0.z, w0.w, p0, p1);
        ch2(A.z, u2.z, w1.x, w1.y, p0, p1);
        ch2(A.w, u2.w, w1.z, w1.w, p0, p1);
        float p = p0 + p1;
#pragma unroll
        for (int off = 8; off >= 1; off >>= 1)
            p += __shfl_xor(p, off);
        if (l16 == 0) out[pa.y] = p + be2;
    }
}

// ---------------------------------------------------------------------------
// K9: classifier
// ---------------------------------------------------------------------------
__global__ __launch_bounds__(256) void classify(
    const float* __restrict__ gsum, const float* __restrict__ gcnt,
    const float* __restrict__ W_cls, const float* __restrict__ b_cls,
    float* __restrict__ out)
{
    const int t = threadIdx.x;
    if (t >= N_GRAPHS * N_CLASSES) return;
    const int g = t / N_CLASSES;
    const int c = t % N_CLASSES;
    const float inv = 1.0f / fmaxf(gcnt[g], 1.0f);
    float acc = 0.f;
    for (int k = 0; k < DIM; ++k)
        acc += gsum[g * DIM + k] * W_cls[k * N_CLASSES + c];
    out[g * N_CLASSES + c] = acc * inv + b_cls[c];
}

// ---------------------------------------------------------------------------
extern "C" void kernel_launch(void* const* d_in, const int* in_sizes, int n_in,
                              void* d_out, int out_size, void* d_ws, size_t ws_size,
                              hipStream_t stream)
{
    const float* x      = (const float*)d_in[0];
    const int*   eidx   = (const int*)  d_in[1];
    const int*   bid    = (const int*)  d_in[2];
    const float* W_in   = (const float*)d_in[3];
    const float* W_self = (const float*)d_in[4];
    const float* b      = (const float*)d_in[5];
    const float* W_e1   = (const float*)d_in[6];
    const float* b_e1   = (const float*)d_in[7];
    const float* W_e2   = (const float*)d_in[8];
    const float* b_e2   = (const float*)d_in[9];
    const float* W_cls  = (const float*)d_in[10];
    const float* b_cls  = (const float*)d_in[11];
    float* out = (float*)d_out;

    char* ws = (char*)d_ws;
    int*    cnt    = (int*)   (ws);                         // 40000 B
    float*  gsum   = (float*) (ws + 40960);                 // 8192 B
    float*  gcnt   = (float*) (ws + 49152);                 // 64 B
    int*    cursor = (int*)   (ws + 65536);                 // 40000 B
    uint2*  pairs  = (uint2*) (ws + 131072);                // 5,120,000 B
    float*  XAGG   = (float*) (ws + 131072 + 5120000);      // 5,120,000 B
    ushort* U12    = (ushort*)(ws + 131072 + 10240000);     // 5,120,000 B
    uint*   xb     = (uint*)  (ws + 131072 + 15360000);     // 2,560,000 B

    const int* src = eidx;
    const int* dst = eidx + N_EDGES;

    hipMemsetAsync(d_ws, 0, 65536, stream);   // cnt + gsum + gcnt

    conv_bf16  <<<(N_NODES * DIM / 4) / 256, 256, 0, stream>>>(x, xb);
    hist_dst   <<<N_EDGES / 1024, 256, 0, stream>>>(dst, cnt);
    count_nodes<<<1, 256, 0, stream>>>(bid, gcnt);
    scan_k     <<<1, 1024, 0, stream>>>(cnt, cursor);
    fill_csr   <<<N_EDGES / 1024, 256, 0, stream>>>(src, dst, cursor, pairs);
    gather_xb  <<<N_NODES / 4, 256, 0, stream>>>(xb, cnt, cursor, pairs, XAGG);
    gemm_zu    <<<N_NODES / ZROWS, 256, 0, stream>>>(XAGG, x, W_in, W_self, b, bid,
                                                     W_e1, b_e1, gsum, U12);
    edge_mlp4  <<<N_NODES / 16, 256, 0, stream>>>(U12, cnt, cursor, pairs, W_e2, b_e2, out);
    classify   <<<1, 256, 0, stream>>>(gsum, gcnt, W_cls, b_cls, out + N_EDGES);
}

// Round 18
// 262.067 us; speedup vs baseline: 1.0775x; 1.0775x over previous
//
#include <hip/hip_runtime.h>

#define N_NODES   10000
#define N_EDGES   640000
#define DIM       128
#define N_GRAPHS  16
#define N_CLASSES 10

typedef unsigned int uint;
typedef unsigned short ushort;

__device__ __forceinline__ float bf2f(uint lo16) {
    return __uint_as_float(lo16 << 16);
}
__device__ __forceinline__ ushort f2bf(float f) {
    uint u = __float_as_uint(f);
    u += 0x7fffu + ((u >> 16) & 1u);      // round-to-nearest-even
    return (ushort)(u >> 16);
}

// ---------------------------------------------------------------------------
// K0: x (fp32) -> xb (bf16, 2.56 MB: fits per-XCD L2). uint = 2 channels.
// ---------------------------------------------------------------------------
__global__ __launch_bounds__(256) void conv_bf16(
    const float* __restrict__ x, uint* __restrict__ xb)
{
    const int idx = blockIdx.x * 256 + threadIdx.x;     // 1250 blocks exact
    const float4 v = ((const float4*)x)[idx];
    uint lo = (uint)f2bf(v.x) | ((uint)f2bf(v.y) << 16);
    uint hi = (uint)f2bf(v.z) | ((uint)f2bf(v.w) << 16);
    ((uint2*)xb)[idx] = make_uint2(lo, hi);
}

// ---------------------------------------------------------------------------
// K1: histogram of dst — 4 edges/thread
// ---------------------------------------------------------------------------
__global__ __launch_bounds__(256) void hist_dst(
    const int* __restrict__ dst, int* __restrict__ cnt)
{
    const int base = (blockIdx.x * 256 + threadIdx.x) * 4;   // 625 blocks exact
    const int d0 = dst[base + 0];
    const int d1 = dst[base + 1];
    const int d2 = dst[base + 2];
    const int d3 = dst[base + 3];
    atomicAdd(&cnt[d0], 1);
    atomicAdd(&cnt[d1], 1);
    atomicAdd(&cnt[d2], 1);
    atomicAdd(&cnt[d3], 1);
}

// ---------------------------------------------------------------------------
// K2: per-graph node counts (batch_ids) -> gcnt (float)
// ---------------------------------------------------------------------------
__global__ __launch_bounds__(256) void count_nodes(
    const int* __restrict__ bid, float* __restrict__ gcnt)
{
    __shared__ int h[N_GRAPHS];
    const int t = threadIdx.x;
    if (t < N_GRAPHS) h[t] = 0;
    __syncthreads();
    for (int n = t; n < N_NODES; n += 256) atomicAdd(&h[bid[n]], 1);
    __syncthreads();
    if (t < N_GRAPHS) gcnt[t] = (float)h[t];
}

// ---------------------------------------------------------------------------
// K3: exclusive prefix sum of cnt[10000] -> cursor (single block)
// ---------------------------------------------------------------------------
__global__ __launch_bounds__(1024) void scan_k(
    const int* __restrict__ cnt, int* __restrict__ cursor)
{
    __shared__ int s[1024];
    const int t = threadIdx.x;
    int local[10];
    int sum = 0;
    if (t < 1000) {
        for (int j = 0; j < 10; ++j) { local[j] = sum; sum += cnt[t * 10 + j]; }
    }
    s[t] = (t < 1000) ? sum : 0;
    __syncthreads();
    for (int st = 1; st < 1024; st <<= 1) {
        int v = (t >= st) ? s[t - st] : 0;
        __syncthreads();
        s[t] += v;
        __syncthreads();
    }
    if (t < 1000) {
        const int off = (t == 0) ? 0 : s[t - 1];
        for (int j = 0; j < 10; ++j) cursor[t * 10 + j] = off + local[j];
    }
}

// ---------------------------------------------------------------------------
// K4: fill CSR — 4 edges/thread; srcs[pos] = src, grouped by dst (4B payload)
// ---------------------------------------------------------------------------
__global__ __launch_bounds__(256) void fill_csr(
    const int* __restrict__ src, const int* __restrict__ dst,
    int* __restrict__ cursor, uint* __restrict__ srcs)
{
    const int base = (blockIdx.x * 256 + threadIdx.x) * 4;   // 625 blocks exact
    const int d0 = dst[base + 0];
    const int d1 = dst[base + 1];
    const int d2 = dst[base + 2];
    const int d3 = dst[base + 3];
    const int s0 = src[base + 0];
    const int s1 = src[base + 1];
    const int s2 = src[base + 2];
    const int s3 = src[base + 3];
    const int p0 = atomicAdd(&cursor[d0], 1);
    const int p1 = atomicAdd(&cursor[d1], 1);
    const int p2 = atomicAdd(&cursor[d2], 1);
    const int p3 = atomicAdd(&cursor[d3], 1);
    srcs[p0] = (uint)s0;
    srcs[p1] = (uint)s1;
    srcs[p2] = (uint)s2;
    srcs[p3] = (uint)s3;
}

// ---------------------------------------------------------------------------
// K5: XAGG[n] = sum over in-edges of xb[src]. Wave per node; 8-deep unroll.
// ---------------------------------------------------------------------------
__global__ __launch_bounds__(256) void gather_xb(
    const uint* __restrict__ xb,
    const int* __restrict__ cnt, const int* __restrict__ cursor,
    const uint* __restrict__ srcs,
    float* __restrict__ XAGG)
{
    const int n    = blockIdx.x * 4 + (threadIdx.x >> 6);
    const int lane = threadIdx.x & 63;
    const int end  = cursor[n];
    int i = end - cnt[n];

    float a0 = 0.f, b0 = 0.f, a1 = 0.f, b1 = 0.f;
    float a2 = 0.f, b2 = 0.f, a3 = 0.f, b3 = 0.f;

    for (; i + 8 <= end; i += 8) {
        const uint v0 = xb[srcs[i + 0] * 64 + lane];
        const uint v1 = xb[srcs[i + 1] * 64 + lane];
        const uint v2 = xb[srcs[i + 2] * 64 + lane];
        const uint v3 = xb[srcs[i + 3] * 64 + lane];
        const uint v4 = xb[srcs[i + 4] * 64 + lane];
        const uint v5 = xb[srcs[i + 5] * 64 + lane];
        const uint v6 = xb[srcs[i + 6] * 64 + lane];
        const uint v7 = xb[srcs[i + 7] * 64 + lane];
        a0 += bf2f(v0 & 0xffffu); b0 += bf2f(v0 >> 16);
        a1 += bf2f(v1 & 0xffffu); b1 += bf2f(v1 >> 16);
        a2 += bf2f(v2 & 0xffffu); b2 += bf2f(v2 >> 16);
        a3 += bf2f(v3 & 0xffffu); b3 += bf2f(v3 >> 16);
        a0 += bf2f(v4 & 0xffffu); b0 += bf2f(v4 >> 16);
        a1 += bf2f(v5 & 0xffffu); b1 += bf2f(v5 >> 16);
        a2 += bf2f(v6 & 0xffffu); b2 += bf2f(v6 >> 16);
        a3 += bf2f(v7 & 0xffffu); b3 += bf2f(v7 >> 16);
    }
    for (; i < end; ++i) {
        const uint v = xb[srcs[i] * 64 + lane];
        a0 += bf2f(v & 0xffffu); b0 += bf2f(v >> 16);
    }
    float2 s;
    s.x = (a0 + a1) + (a2 + a3);
    s.y = (b0 + b1) + (b2 + b3);
    *(float2*)&XAGG[n * DIM + lane * 2] = s;
}

// ---------------------------------------------------------------------------
// K6: fused (8 rows/block, 1250 blocks):
//     z = relu(XAGG@W_in + x@W_self + b)  (LDS only)
//     + per-graph sums (run-compressed atomics)
//     + U12 = z @ [W_e1_top | W_e1_bot] (+b_e1), bf16 interleaved
// ---------------------------------------------------------------------------
#define ZROWS 8
__global__ __launch_bounds__(256) void gemm_zu(
    const float* __restrict__ XAGG_in, const float* __restrict__ x,
    const float* __restrict__ W_in, const float* __restrict__ W_self,
    const float* __restrict__ b, const int* __restrict__ bid,
    const float* __restrict__ W_e1, const float* __restrict__ b_e1,
    float* __restrict__ gsum, ushort* __restrict__ U12)
{
    __shared__ float sa[ZROWS * DIM];
    __shared__ float sb[ZROWS * DIM];
    __shared__ int sbid[ZROWS];
    const int base = blockIdx.x * ZROWS;
    const int t = threadIdx.x;
    {
        const float4* ga = (const float4*)(XAGG_in + base * DIM);
        const float4* gb = (const float4*)(x + base * DIM);
        float4* la = (float4*)sa;
        float4* lb = (float4*)sb;
        for (int i = t; i < ZROWS * DIM / 4; i += 256) { la[i] = ga[i]; lb[i] = gb[i]; }
        if (t < ZROWS) sbid[t] = bid[base + t];
    }
    __syncthreads();

    const int half = t >> 7, c = t & 127;

    // --- matmul 1: half0 = XAGG@W_in, half1 = x@W_self ---
    {
        const float* __restrict__ W = half ? W_self : W_in;
        const float4* A4 = (const float4*)(half ? sb : sa);
        float acc[ZROWS];
#pragma unroll
        for (int r = 0; r < ZROWS; ++r) acc[r] = 0.f;
        for (int k4 = 0; k4 < DIM / 4; ++k4) {
            const float w0 = W[(k4 * 4 + 0) * DIM + c];
            const float w1 = W[(k4 * 4 + 1) * DIM + c];
            const float w2 = W[(k4 * 4 + 2) * DIM + c];
            const float w3 = W[(k4 * 4 + 3) * DIM + c];
#pragma unroll
            for (int r = 0; r < ZROWS; ++r) {
                const float4 xv = A4[r * (DIM / 4) + k4];
                acc[r] = fmaf(xv.x, w0, acc[r]);
                acc[r] = fmaf(xv.y, w1, acc[r]);
                acc[r] = fmaf(xv.z, w2, acc[r]);
                acc[r] = fmaf(xv.w, w3, acc[r]);
            }
        }
        __syncthreads();
        if (half) {
#pragma unroll
            for (int r = 0; r < ZROWS; ++r) sb[r * DIM + c] = acc[r];
        }
        __syncthreads();
        if (!half) {
            const float bv = b[c];
            float run = 0.f;
            int cur = sbid[0];
#pragma unroll
            for (int r = 0; r < ZROWS; ++r) {
                const float z = fmaxf(acc[r] + sb[r * DIM + c] + bv, 0.f);
                sa[r * DIM + c] = z;                    // z lives in LDS only
                const int g = sbid[r];
                if (g != cur) { unsafeAtomicAdd(&gsum[cur * DIM + c], run); run = 0.f; cur = g; }
                run += z;
            }
            unsafeAtomicAdd(&gsum[cur * DIM + c], run);
        }
        __syncthreads();
    }

    // --- matmul 2: U12 = z @ [W_e1_top | W_e1_bot] ---
    {
        const float* __restrict__ W = W_e1 + half * 128 * DIM;
        const float4* Z4 = (const float4*)sa;
        float acc[ZROWS];
#pragma unroll
        for (int r = 0; r < ZROWS; ++r) acc[r] = 0.f;
        for (int k4 = 0; k4 < DIM / 4; ++k4) {
            const float w0 = W[(k4 * 4 + 0) * DIM + c];
            const float w1 = W[(k4 * 4 + 1) * DIM + c];
            const float w2 = W[(k4 * 4 + 2) * DIM + c];
            const float w3 = W[(k4 * 4 + 3) * DIM + c];
#pragma unroll
            for (int r = 0; r < ZROWS; ++r) {
                const float4 xv = Z4[r * (DIM / 4) + k4];
                acc[r] = fmaf(xv.x, w0, acc[r]);
                acc[r] = fmaf(xv.y, w1, acc[r]);
                acc[r] = fmaf(xv.z, w2, acc[r]);
                acc[r] = fmaf(xv.w, w3, acc[r]);
            }
        }
        const float bv = half ? 0.f : b_e1[c];
        for (int r = 0; r < ZROWS; ++r)
            U12[(base + r) * 256 + half * 128 + c] = f2bf(acc[r] + bv);
    }
}

// ---------------------------------------------------------------------------
// K8: natural-order edge MLP, 16 lanes per edge, 2 edges per group.
// 4 independent 16B row-loads in flight per lane; uniform work; 20000 blocks;
// lane0 stores float2 (coalesced pairs).
// ---------------------------------------------------------------------------
__device__ __forceinline__ void ch2(uint a, uint b, float wl, float wh,
                                    float& accl, float& acch)
{
    const float fl = fmaxf(__uint_as_float(a << 16) + __uint_as_float(b << 16), 0.f);
    const float fh = fmaxf(__uint_as_float(a & 0xffff0000u) + __uint_as_float(b & 0xffff0000u), 0.f);
    accl = fmaf(fl, wl, accl);
    acch = fmaf(fh, wh, acch);
}

__global__ __launch_bounds__(256) void edge_mlp5(
    const ushort* __restrict__ U12,
    const int* __restrict__ src, const int* __restrict__ dst,
    const float* __restrict__ W_e2, const float* __restrict__ b_e2,
    float* __restrict__ out)
{
    __shared__ float ws[DIM];
    const int t = threadIdx.x;
    if (t < DIM) ws[t] = W_e2[t];
    __syncthreads();

    const int l16 = t & 15;
    const int grp = t >> 4;                        // 0..15
    const int e0  = blockIdx.x * 32 + grp * 2;     // grid = 20000
    const int e1  = e0 + 1;

    const int s0 = src[e0], d0 = dst[e0];
    const int s1 = src[e1], d1 = dst[e1];

    const uint4 A0 = *(const uint4*)(U12 + s0 * 256 + l16 * 8);
    const uint4 B0 = *(const uint4*)(U12 + d0 * 256 + 128 + l16 * 8);
    const uint4 A1 = *(const uint4*)(U12 + s1 * 256 + l16 * 8);
    const uint4 B1 = *(const uint4*)(U12 + d1 * 256 + 128 + l16 * 8);
    const float4 w0 = ((const float4*)ws)[l16 * 2 + 0];
    const float4 w1 = ((const float4*)ws)[l16 * 2 + 1];

    float p0 = 0.f, p1 = 0.f, q0 = 0.f, q1 = 0.f;
    ch2(A0.x, B0.x, w0.x, w0.y, p0, p1);
    ch2(A0.y, B0.y, w0.z, w0.w, p0, p1);
    ch2(A0.z, B0.z, w1.x, w1.y, p0, p1);
    ch2(A0.w, B0.w, w1.z, w1.w, p0, p1);
    ch2(A1.x, B1.x, w0.x, w0.y, q0, q1);
    ch2(A1.y, B1.y, w0.z, w0.w, q0, q1);
    ch2(A1.z, B1.z, w1.x, w1.y, q0, q1);
    ch2(A1.w, B1.w, w1.z, w1.w, q0, q1);

    float p = p0 + p1;
    float q = q0 + q1;
#pragma unroll
    for (int off = 8; off >= 1; off >>= 1) {
        p += __shfl_xor(p, off);
        q += __shfl_xor(q, off);
    }

    if (l16 == 0) {
        const float be2 = b_e2[0];
        *(float2*)&out[e0] = make_float2(p + be2, q + be2);
    }
}

// ---------------------------------------------------------------------------
// K9: classifier
// ---------------------------------------------------------------------------
__global__ __launch_bounds__(256) void classify(
    const float* __restrict__ gsum, const float* __restrict__ gcnt,
    const float* __restrict__ W_cls, const float* __restrict__ b_cls,
    float* __restrict__ out)
{
    const int t = threadIdx.x;
    if (t >= N_GRAPHS * N_CLASSES) return;
    const int g = t / N_CLASSES;
    const int c = t % N_CLASSES;
    const float inv = 1.0f / fmaxf(gcnt[g], 1.0f);
    float acc = 0.f;
    for (int k = 0; k < DIM; ++k)
        acc += gsum[g * DIM + k] * W_cls[k * N_CLASSES + c];
    out[g * N_CLASSES + c] = acc * inv + b_cls[c];
}

// ---------------------------------------------------------------------------
extern "C" void kernel_launch(void* const* d_in, const int* in_sizes, int n_in,
                              void* d_out, int out_size, void* d_ws, size_t ws_size,
                              hipStream_t stream)
{
    const float* x      = (const float*)d_in[0];
    const int*   eidx   = (const int*)  d_in[1];
    const int*   bid    = (const int*)  d_in[2];
    const float* W_in   = (const float*)d_in[3];
    const float* W_self = (const float*)d_in[4];
    const float* b      = (const float*)d_in[5];
    const float* W_e1   = (const float*)d_in[6];
    const float* b_e1   = (const float*)d_in[7];
    const float* W_e2   = (const float*)d_in[8];
    const float* b_e2   = (const float*)d_in[9];
    const float* W_cls  = (const float*)d_in[10];
    const float* b_cls  = (const float*)d_in[11];
    float* out = (float*)d_out;

    char* ws = (char*)d_ws;
    int*    cnt    = (int*)   (ws);                         // 40000 B
    float*  gsum   = (float*) (ws + 40960);                 // 8192 B
    float*  gcnt   = (float*) (ws + 49152);                 // 64 B
    int*    cursor = (int*)   (ws + 65536);                 // 40000 B
    uint*   srcs   = (uint*)  (ws + 131072);                // 2,560,000 B
    float*  XAGG   = (float*) (ws + 131072 + 2560000);      // 5,120,000 B
    ushort* U12    = (ushort*)(ws + 131072 + 7680000);      // 5,120,000 B
    uint*   xb     = (uint*)  (ws + 131072 + 12800000);     // 2,560,000 B

    const int* src = eidx;
    const int* dst = eidx + N_EDGES;

    hipMemsetAsync(d_ws, 0, 65536, stream);   // cnt + gsum + gcnt

    conv_bf16  <<<(N_NODES * DIM / 4) / 256, 256, 0, stream>>>(x, xb);
    hist_dst   <<<N_EDGES / 1024, 256, 0, stream>>>(dst, cnt);
    count_nodes<<<1, 256, 0, stream>>>(bid, gcnt);
    scan_k     <<<1, 1024, 0, stream>>>(cnt, cursor);
    fill_csr   <<<N_EDGES / 1024, 256, 0, stream>>>(src, dst, cursor, srcs);
    gather_xb  <<<N_NODES / 4, 256, 0, stream>>>(xb, cnt, cursor, srcs, XAGG);
    gemm_zu    <<<N_NODES / ZROWS, 256, 0, stream>>>(XAGG, x, W_in, W_self, b, bid,
                                                     W_e1, b_e1, gsum, U12);
    edge_mlp5  <<<N_EDGES / 32, 256, 0, stream>>>(U12, src, dst, W_e2, b_e2, out);
    classify   <<<1, 256, 0, stream>>>(gsum, gcnt, W_cls, b_cls, out + N_EDGES);
}